// Round 8
// baseline (426.992 us; speedup 1.0000x reference)
//
#include <hip/hip_runtime.h>
#include <hip/hip_bf16.h>
#include <math.h>

#define N_NODES 20000
#define N_EDGES 256000
#define LOG2E 1.4426950408889634f

typedef __attribute__((ext_vector_type(8))) __bf16 bf16x8;
typedef __attribute__((ext_vector_type(8))) unsigned short u16x8;
typedef __attribute__((ext_vector_type(4))) float f32x4;

static __device__ __forceinline__ unsigned short f2bf(float f) {
  unsigned u = __float_as_uint(f);
  unsigned r = (u + 0x7fffu + ((u >> 16) & 1u)) >> 16;
  return (unsigned short)r;
}
static __device__ __forceinline__ float b2f(unsigned short u) {
  return __uint_as_float((unsigned)u << 16);
}

// ---------------- fused setup: tables | tws1 | twqkv | hist ----------------
// segments: [0,1) tables, [1,1025) tws1, [1025,1793) twqkv, [1793,2793) hist
__global__ __launch_bounds__(256) void k_setup(
    const float* __restrict__ rel_emb, const float* __restrict__ sa_We,
    const float* __restrict__ We_gt, const float* __restrict__ Ws1,
    const float* __restrict__ Wq, const float* __restrict__ Wk,
    const float* __restrict__ Wv, const int* __restrict__ e_dst,
    float* __restrict__ saTab, float* __restrict__ epTab,
    ushort* __restrict__ Ws1t, ushort* __restrict__ Wt,
    int* __restrict__ deg) {
  int b = blockIdx.x;
  int t = threadIdx.x;
  if (b == 0) {
    {
      int l = t >> 7, r = (t >> 3) & 15, h = t & 7;
      float acc = 0.f;
      for (int p = 0; p < 32; ++p)
        acc += rel_emb[r * 32 + p] * sa_We[l * 256 + p * 8 + h];
      saTab[t] = acc * LOG2E;
    }
    for (int r = 0; r < 16; ++r) {
      float acc = 0.f;
      for (int p = 0; p < 32; ++p)
        acc += rel_emb[r * 32 + p] * We_gt[p * 256 + t];
      epTab[r * 256 + t] = acc;
    }
  } else if (b < 1025) {
    int lb = b - 1;
    int h = lb >> 7, kcol = lb & 127;
    Ws1t[((size_t)h * 128 + kcol) * 256 + t] =
        f2bf(Ws1[((size_t)h * 256 + t) * 128 + kcol]);
  } else if (b < 1793) {
    int lb = b - 1025;
    int m = lb >> 8, n = lb & 255;
    const float* W = (m == 0) ? Wq : (m == 1) ? Wk : Wv;
    Wt[((size_t)m * 256 + n) * 256 + t] = f2bf(W[(size_t)t * 256 + n]);
  } else {
    int e = (b - 1793) * 256 + t;
    if (e < N_EDGES) atomicAdd(&deg[e_dst[e]], 1);
  }
}

__global__ __launch_bounds__(1024) void k_scan(const int* __restrict__ deg,
                                               int* __restrict__ rowPtr,
                                               int* __restrict__ cursor) {
  const int CH = (N_NODES + 1023) / 1024;  // 20
  int t = threadIdx.x;
  int b0 = t * CH, b1 = min(b0 + CH, N_NODES);
  int s = 0;
  for (int i = b0; i < b1; ++i) s += deg[i];
  __shared__ int part[1024];
  part[t] = s;
  __syncthreads();
  for (int off = 1; off < 1024; off <<= 1) {
    int add = (t >= off) ? part[t - off] : 0;
    __syncthreads();
    part[t] += add;
    __syncthreads();
  }
  int run = (t == 0) ? 0 : part[t - 1];
  for (int i = b0; i < b1; ++i) {
    rowPtr[i] = run;
    cursor[i] = run;
    run += deg[i];
  }
  if (t == 0) rowPtr[N_NODES] = part[1023];
}

__global__ void k_fill(const int* __restrict__ e_dst, const int* __restrict__ e_src,
                       const int* __restrict__ e_type, int* __restrict__ cursor,
                       int2* __restrict__ csrPack) {
  int e = blockIdx.x * 256 + threadIdx.x;
  if (e >= N_EDGES) return;
  int d = e_dst[e];
  int pos = atomicAdd(&cursor[d], 1);
  csrPack[pos] = make_int2(e_src[e], e_type[e]);
}

// ---------------- fused GEMM: barrier-free, register-resident A ----------------
// grid (157, 4): block = 128 nodes; wave owns 32 rows.
// y=0: MLP heads 0-3 (A=Xs); y=1: MLP heads 4-7 (A=Xs);
// y=2: QKV slices 0-2 (A=Xm); y=3: QKV slices 3-5 (A=Xm).
__global__ __launch_bounds__(256) void k_gemm(
    const float* __restrict__ Xs, const float* __restrict__ Xm,
    const ushort* __restrict__ Ws1t, const ushort* __restrict__ Wqkvt,
    const float* __restrict__ bs1, const float* __restrict__ Ws2,
    const float* __restrict__ bs2, const float* __restrict__ bq,
    const float* __restrict__ bk, const float* __restrict__ bv,
    float* __restrict__ h0, float* __restrict__ q, ushort* __restrict__ kvB) {
  int tid = threadIdx.x;
  int y = blockIdx.y;
  bool isMlp = (y < 2);
  int base = blockIdx.x * 128;
  int wv = tid >> 6, lane = tid & 63;
  int l15 = lane & 15, lhi = lane >> 4;

  // ---- load A: 32 rows x 256 K into registers (bf16), converted from f32 ----
  const float* Xsrc = isMlp ? Xs : Xm;
  bf16x8 A[2][8];  // [mr][kk]
  #pragma unroll
  for (int mr = 0; mr < 2; ++mr) {
    int row = base + wv * 32 + mr * 16 + l15;
    bool ok = row < N_NODES;
    const float* rp = Xsrc + (size_t)row * 256;
    #pragma unroll
    for (int kk = 0; kk < 8; ++kk) {
      float4 x0 = {0.f, 0.f, 0.f, 0.f}, x1 = {0.f, 0.f, 0.f, 0.f};
      if (ok) {
        x0 = *(const float4*)(rp + kk * 32 + lhi * 8);
        x1 = *(const float4*)(rp + kk * 32 + lhi * 8 + 4);
      }
      u16x8 tmp;
      tmp[0] = f2bf(x0.x); tmp[1] = f2bf(x0.y); tmp[2] = f2bf(x0.z); tmp[3] = f2bf(x0.w);
      tmp[4] = f2bf(x1.x); tmp[5] = f2bf(x1.y); tmp[6] = f2bf(x1.z); tmp[7] = f2bf(x1.w);
      A[mr][kk] = *(bf16x8*)&tmp;
    }
  }

  if (isMlp) {
    #pragma unroll
    for (int s = 0; s < 4; ++s) {
      int h = y * 4 + s;
      const ushort* Bsrc = Ws1t + (size_t)h * 128 * 256;
      float part[2][4] = {{0.f, 0.f, 0.f, 0.f}, {0.f, 0.f, 0.f, 0.f}};
      #pragma unroll
      for (int p = 0; p < 2; ++p) {
        f32x4 acc[2][4];
        #pragma unroll
        for (int mr = 0; mr < 2; ++mr)
          #pragma unroll
          for (int n4 = 0; n4 < 4; ++n4) acc[mr][n4] = (f32x4){0.f, 0.f, 0.f, 0.f};
        #pragma unroll
        for (int kk = 0; kk < 8; ++kk) {
          #pragma unroll
          for (int n4 = 0; n4 < 4; ++n4) {
            int nt = p * 4 + n4;
            bf16x8 b = *(const bf16x8*)(Bsrc + (size_t)(nt * 16 + l15) * 256 + kk * 32 + lhi * 8);
            acc[0][n4] = __builtin_amdgcn_mfma_f32_16x16x32_bf16(A[0][kk], b, acc[0][n4], 0, 0, 0);
            acc[1][n4] = __builtin_amdgcn_mfma_f32_16x16x32_bf16(A[1][kk], b, acc[1][n4], 0, 0, 0);
          }
        }
        #pragma unroll
        for (int n4 = 0; n4 < 4; ++n4) {
          int c = h * 128 + (p * 4 + n4) * 16 + l15;
          float b1 = bs1[c], w2 = Ws2[c];
          #pragma unroll
          for (int mr = 0; mr < 2; ++mr)
            #pragma unroll
            for (int j = 0; j < 4; ++j)
              part[mr][j] += fmaxf(acc[mr][n4][j] + b1, 0.f) * w2;
        }
      }
      #pragma unroll
      for (int mr = 0; mr < 2; ++mr)
        #pragma unroll
        for (int j = 0; j < 4; ++j) {
          #pragma unroll
          for (int o = 1; o < 16; o <<= 1) part[mr][j] += __shfl_xor(part[mr][j], o);
        }
      if (l15 == 0) {
        float b2 = bs2[h];
        #pragma unroll
        for (int mr = 0; mr < 2; ++mr)
          #pragma unroll
          for (int j = 0; j < 4; ++j) {
            int row = base + wv * 32 + mr * 16 + lhi * 4 + j;
            if (row < N_NODES) h0[(size_t)row * 8 + h] = part[mr][j] + b2;
          }
      }
    }
  } else {
    #pragma unroll
    for (int s4 = 0; s4 < 3; ++s4) {
      int s = (y - 2) * 3 + s4;
      int m = s >> 1, half = s & 1;
      const ushort* Bsrc = Wqkvt + ((size_t)m * 256 + half * 128) * 256;
      const float* bias = (m == 0) ? bq : (m == 1) ? bk : bv;
      #pragma unroll
      for (int p = 0; p < 2; ++p) {
        f32x4 acc[2][4];
        #pragma unroll
        for (int mr = 0; mr < 2; ++mr)
          #pragma unroll
          for (int n4 = 0; n4 < 4; ++n4) acc[mr][n4] = (f32x4){0.f, 0.f, 0.f, 0.f};
        #pragma unroll
        for (int kk = 0; kk < 8; ++kk) {
          #pragma unroll
          for (int n4 = 0; n4 < 4; ++n4) {
            int nt = p * 4 + n4;
            bf16x8 b = *(const bf16x8*)(Bsrc + (size_t)(nt * 16 + l15) * 256 + kk * 32 + lhi * 8);
            acc[0][n4] = __builtin_amdgcn_mfma_f32_16x16x32_bf16(A[0][kk], b, acc[0][n4], 0, 0, 0);
            acc[1][n4] = __builtin_amdgcn_mfma_f32_16x16x32_bf16(A[1][kk], b, acc[1][n4], 0, 0, 0);
          }
        }
        #pragma unroll
        for (int n4 = 0; n4 < 4; ++n4) {
          int c = half * 128 + (p * 4 + n4) * 16 + l15;
          float bc = bias[c];
          #pragma unroll
          for (int mr = 0; mr < 2; ++mr)
            #pragma unroll
            for (int j = 0; j < 4; ++j) {
              int row = base + wv * 32 + mr * 16 + lhi * 4 + j;
              if (row < N_NODES) {
                float val = acc[mr][n4][j] + bc;
                if (m == 0) q[(size_t)row * 256 + c] = val;
                else if (m == 1) kvB[(size_t)row * 512 + c] = f2bf(val);
                else kvB[(size_t)row * 512 + 256 + c] = f2bf(val);
              }
            }
        }
      }
    }
  }
}

// ---------------- SA layers (wave per node: 8 heads x 8 edge-slots, exp2 domain) ----------------

__global__ __launch_bounds__(256) void k_sa(const float* __restrict__ h_in,
                                            float* __restrict__ h_out,
                                            const int* __restrict__ rowPtr,
                                            const int2* __restrict__ csrPack,
                                            const float* __restrict__ sa_w,
                                            const float* __restrict__ sa_al,
                                            const float* __restrict__ sa_ar,
                                            const float* __restrict__ saTab, int layer) {
  int node = blockIdx.x * 4 + (threadIdx.x >> 6);
  int lane = threadIdx.x & 63;
  int h = lane & 7, eslot = lane >> 3;
  float wgt = sa_w[layer * 8 + h];
  float al2 = sa_al[layer * 8 + h] * LOG2E;
  float ar2 = sa_ar[layer * 8 + h] * LOG2E;
  const float* tab = saTab + layer * 128;
  float zd = h_in[(size_t)node * 8 + h] * wgt;
  int s0 = rowPtr[node], s1 = rowPtr[node + 1];
  float m = -1e30f, lsum = 0.f, acc = 0.f;
  for (int i = s0 + eslot; i < s1; i += 8) {
    int2 p = csrPack[i];
    float zs = h_in[(size_t)p.x * 8 + h] * wgt;
    float e = zs * al2 + zd * ar2 + tab[p.y * 8 + h];
    e = (e >= 0.f) ? e : 0.2f * e;
    float nm = fmaxf(m, e);
    float scl = exp2f(m - nm);
    float pw = exp2f(e - nm);
    acc = acc * scl + pw * zs;
    lsum = lsum * scl + pw;
    m = nm;
  }
  #pragma unroll
  for (int off = 8; off < 64; off <<= 1) {
    float om = __shfl_xor(m, off);
    float ol = __shfl_xor(lsum, off);
    float oa = __shfl_xor(acc, off);
    float nm = fmaxf(m, om);
    float sl = exp2f(m - nm);
    float so = exp2f(om - nm);
    acc = acc * sl + oa * so;
    lsum = lsum * sl + ol * so;
    m = nm;
  }
  float o = acc / (lsum + 1e-9f);
  float r = o + zd;
  r = (r > 0.f) ? r : expm1f(r);
  if (layer == 0) {
    r += __shfl_xor(r, 1);
    r += __shfl_xor(r, 2);
    r += __shfl_xor(r, 4);
    r *= 0.125f;
  }
  if (eslot == 0) h_out[(size_t)node * 8 + h] = r;
}

// ---------------- GT edge phase (interleaved bf16 kv gather, exp2 domain) ----------------

__global__ __launch_bounds__(256) void k_gt(const float* __restrict__ q,
                                            const ushort* __restrict__ kvB,
                                            const float* __restrict__ epTab,
                                            const float* __restrict__ feats_sem,
                                            const int* __restrict__ rowPtr,
                                            const int2* __restrict__ csrPack,
                                            ushort* __restrict__ agg) {
  int node = blockIdx.x * 4 + (threadIdx.x >> 6);
  int lane = threadIdx.x & 63;
  int c0 = lane * 4;
  const float SC2 = 0.17677669529663687f * LOG2E;
  float4 qv = *(const float4*)(q + (size_t)node * 256 + c0);
  qv.x *= SC2; qv.y *= SC2; qv.z *= SC2; qv.w *= SC2;
  float4 acc = {0.f, 0.f, 0.f, 0.f};
  float m = -1e30f, lsum = 0.f;
  int s0 = rowPtr[node], s1 = rowPtr[node + 1];
  int i = s0;
  for (; i + 1 < s1; i += 2) {
    int2 eA = csrPack[i], eB = csrPack[i + 1];
    const ushort* rA = kvB + (size_t)eA.x * 512 + c0;
    const ushort* rB = kvB + (size_t)eB.x * 512 + c0;
    ushort4 kA = *(const ushort4*)rA;
    ushort4 kB4 = *(const ushort4*)rB;
    float4 epA = *(const float4*)(epTab + eA.y * 256 + c0);
    float4 epB = *(const float4*)(epTab + eB.y * 256 + c0);
    ushort4 vA = *(const ushort4*)(rA + 256);
    ushort4 vB = *(const ushort4*)(rB + 256);
    float pA = qv.x * b2f(kA.x) * epA.x + qv.y * b2f(kA.y) * epA.y +
               qv.z * b2f(kA.z) * epA.z + qv.w * b2f(kA.w) * epA.w;
    float pB = qv.x * b2f(kB4.x) * epB.x + qv.y * b2f(kB4.y) * epB.y +
               qv.z * b2f(kB4.z) * epB.z + qv.w * b2f(kB4.w) * epB.w;
    pA += __shfl_xor(pA, 1); pB += __shfl_xor(pB, 1);
    pA += __shfl_xor(pA, 2); pB += __shfl_xor(pB, 2);
    pA += __shfl_xor(pA, 4); pB += __shfl_xor(pB, 4);
    float nm = fmaxf(m, fmaxf(pA, pB));
    float scl = exp2f(m - nm);
    float wA = exp2f(pA - nm);
    float wB = exp2f(pB - nm);
    acc.x = acc.x * scl + wA * b2f(vA.x) + wB * b2f(vB.x);
    acc.y = acc.y * scl + wA * b2f(vA.y) + wB * b2f(vB.y);
    acc.z = acc.z * scl + wA * b2f(vA.z) + wB * b2f(vB.z);
    acc.w = acc.w * scl + wA * b2f(vA.w) + wB * b2f(vB.w);
    lsum = lsum * scl + wA + wB;
    m = nm;
  }
  if (i < s1) {
    int2 eA = csrPack[i];
    const ushort* rA = kvB + (size_t)eA.x * 512 + c0;
    ushort4 kv = *(const ushort4*)rA;
    float4 ep = *(const float4*)(epTab + eA.y * 256 + c0);
    ushort4 vv = *(const ushort4*)(rA + 256);
    float part = qv.x * b2f(kv.x) * ep.x + qv.y * b2f(kv.y) * ep.y +
                 qv.z * b2f(kv.z) * ep.z + qv.w * b2f(kv.w) * ep.w;
    part += __shfl_xor(part, 1);
    part += __shfl_xor(part, 2);
    part += __shfl_xor(part, 4);
    float nm = fmaxf(m, part);
    float scl = exp2f(m - nm);
    float pw = exp2f(part - nm);
    acc.x = acc.x * scl + pw * b2f(vv.x);
    acc.y = acc.y * scl + pw * b2f(vv.y);
    acc.z = acc.z * scl + pw * b2f(vv.z);
    acc.w = acc.w * scl + pw * b2f(vv.w);
    lsum = lsum * scl + pw;
    m = nm;
  }
  float inv = 1.f / (lsum + 1e-9f);
  float4 fs = *(const float4*)(feats_sem + (size_t)node * 256 + c0);
  ushort4 r;
  r.x = f2bf(acc.x * inv + fs.x);
  r.y = f2bf(acc.y * inv + fs.y);
  r.z = f2bf(acc.z * inv + fs.z);
  r.w = f2bf(acc.w * inv + fs.w);
  *(ushort4*)(agg + (size_t)node * 256 + c0) = r;
}

__global__ void k_bnstats(const ushort* __restrict__ agg, double* __restrict__ colsum,
                          double* __restrict__ colssq) {
  int t = threadIdx.x;
  int r0 = blockIdx.x * 79;
  int r1 = min(r0 + 79, N_NODES);
  double s = 0.0, qq = 0.0;
  for (int r = r0; r < r1; ++r) {
    float x = b2f(agg[(size_t)r * 256 + t]);
    s += (double)x;
    qq += (double)x * (double)x;
  }
  atomicAdd(&colsum[t], s);
  atomicAdd(&colssq[t], qq);
}

__global__ void k_bnfinal(const double* __restrict__ colsum, const double* __restrict__ colssq,
                          float* __restrict__ muArr, float* __restrict__ invArr) {
  int t = threadIdx.x;
  double mu = colsum[t] / (double)N_NODES;
  double var = colssq[t] / (double)N_NODES - mu * mu;
  muArr[t] = (float)mu;
  invArr[t] = (float)(1.0 / sqrt(var + 1e-5));
}

__global__ __launch_bounds__(256) void k_final(const ushort* __restrict__ agg,
                                               const float* __restrict__ muArr,
                                               const float* __restrict__ invArr,
                                               const float* __restrict__ bn_gamma,
                                               const float* __restrict__ bn_beta,
                                               const float* __restrict__ Wout,
                                               const float* __restrict__ bout,
                                               const float* __restrict__ hB,
                                               const float* __restrict__ cent,
                                               const float* __restrict__ gamma,
                                               const float* __restrict__ beta,
                                               float* __restrict__ out) {
  int node = blockIdx.x * 4 + (threadIdx.x >> 6);
  int lane = threadIdx.x & 63;
  int c0 = lane * 4;
  ushort4 xa = *(const ushort4*)(agg + (size_t)node * 256 + c0);
  float4 mu = *(const float4*)(muArr + c0);
  float4 iv = *(const float4*)(invArr + c0);
  float4 g = *(const float4*)(bn_gamma + c0);
  float4 b = *(const float4*)(bn_beta + c0);
  float4 w = *(const float4*)(Wout + c0);
  float p = fmaxf((b2f(xa.x) - mu.x) * iv.x * g.x + b.x, 0.f) * w.x +
            fmaxf((b2f(xa.y) - mu.y) * iv.y * g.y + b.y, 0.f) * w.y +
            fmaxf((b2f(xa.z) - mu.z) * iv.z * g.z + b.z, 0.f) * w.z +
            fmaxf((b2f(xa.w) - mu.w) * iv.w * g.w + b.w, 0.f) * w.w;
  #pragma unroll
  for (int o = 1; o < 64; o <<= 1) p += __shfl_xor(p, o);
  float ls = p + bout[0];
  int h = lane & 7;
  float logit = 0.5f * hB[(size_t)node * 8 + h] + 0.5f * ls;
  float sc = (cent[node] * gamma[h] + beta[h]) * logit;
  sc += __shfl_xor(sc, 1);
  sc += __shfl_xor(sc, 2);
  sc += __shfl_xor(sc, 4);
  float mn = sc * 0.125f;
  mn = (mn >= 0.f) ? mn : 0.01f * mn;
  if (lane == 0) out[node] = mn;
}

// ---------------- launch ----------------

extern "C" void kernel_launch(void* const* d_in, const int* in_sizes, int n_in,
                              void* d_out, int out_size, void* d_ws, size_t ws_size,
                              hipStream_t stream) {
  (void)in_sizes; (void)n_in; (void)out_size; (void)ws_size;
  const float* feats_struct = (const float*)d_in[0];
  const float* feats_sem    = (const float*)d_in[1];
  const float* cent         = (const float*)d_in[2];
  const float* Ws1          = (const float*)d_in[3];
  const float* bs1          = (const float*)d_in[4];
  const float* Ws2          = (const float*)d_in[5];
  const float* bs2          = (const float*)d_in[6];
  const float* rel_emb      = (const float*)d_in[7];
  const float* sa_w         = (const float*)d_in[8];
  const float* sa_al        = (const float*)d_in[9];
  const float* sa_ar        = (const float*)d_in[10];
  const float* sa_We        = (const float*)d_in[11];
  const float* Wq           = (const float*)d_in[12];
  const float* bq           = (const float*)d_in[13];
  const float* Wk           = (const float*)d_in[14];
  const float* bk           = (const float*)d_in[15];
  const float* Wv           = (const float*)d_in[16];
  const float* bv           = (const float*)d_in[17];
  const float* We_gt        = (const float*)d_in[18];
  const float* bn_gamma     = (const float*)d_in[19];
  const float* bn_beta      = (const float*)d_in[20];
  const float* Wout         = (const float*)d_in[21];
  const float* bout         = (const float*)d_in[22];
  const float* gamma        = (const float*)d_in[23];
  const float* beta         = (const float*)d_in[24];
  const int* e_type         = (const int*)d_in[25];
  const int* e_src          = (const int*)d_in[26];
  const int* e_dst          = (const int*)d_in[27];
  float* out = (float*)d_out;

  char* wsb = (char*)d_ws;
  size_t off = 0;
  auto alloc = [&](size_t bytes) -> char* {
    char* p = wsb + off;
    off = (off + bytes + 255) & ~(size_t)255;
    return p;
  };
  float* saTab   = (float*)alloc(2 * 16 * 8 * 4);
  float* epTab   = (float*)alloc(16 * 256 * 4);
  int* deg       = (int*)alloc((size_t)N_NODES * 4);
  int* rowPtr    = (int*)alloc((size_t)(N_NODES + 1) * 4);
  int* cursor    = (int*)alloc((size_t)N_NODES * 4);
  int2* csrPack  = (int2*)alloc((size_t)N_EDGES * 8);
  float* h0      = (float*)alloc((size_t)N_NODES * 8 * 4);
  float* hA      = (float*)alloc((size_t)N_NODES * 8 * 4);
  float* hB      = (float*)alloc((size_t)N_NODES * 8 * 4);
  float* qb      = (float*)alloc((size_t)N_NODES * 256 * 4);
  ushort* kvB    = (ushort*)alloc((size_t)N_NODES * 512 * 2);
  ushort* agg    = (ushort*)alloc((size_t)N_NODES * 256 * 2);
  double* colsum = (double*)alloc(256 * 8);
  double* colssq = (double*)alloc(256 * 8);
  float* muArr   = (float*)alloc(256 * 4);
  float* invArr  = (float*)alloc(256 * 4);
  ushort* Ws1t   = (ushort*)alloc((size_t)8 * 128 * 256 * 2);
  ushort* Wqkvt  = (ushort*)alloc((size_t)3 * 256 * 256 * 2);

  hipMemsetAsync(deg, 0, (size_t)N_NODES * 4, stream);
  hipMemsetAsync(colsum, 0, 256 * 8, stream);
  hipMemsetAsync(colssq, 0, 256 * 8, stream);

  k_setup<<<2793, 256, 0, stream>>>(rel_emb, sa_We, We_gt, Ws1, Wq, Wk, Wv, e_dst,
                                    saTab, epTab, Ws1t, Wqkvt, deg);
  k_scan<<<1, 1024, 0, stream>>>(deg, rowPtr, cursor);
  k_fill<<<(N_EDGES + 255) / 256, 256, 0, stream>>>(e_dst, e_src, e_type, cursor, csrPack);

  const int MT = (N_NODES + 127) / 128;  // 157
  dim3 gGemm(MT, 4);
  k_gemm<<<gGemm, 256, 0, stream>>>(feats_struct, feats_sem, Ws1t, Wqkvt,
                                    bs1, Ws2, bs2, bq, bk, bv, h0, qb, kvB);
  k_sa<<<(N_NODES + 3) / 4, 256, 0, stream>>>(h0, hA, rowPtr, csrPack,
                                              sa_w, sa_al, sa_ar, saTab, 0);
  k_sa<<<(N_NODES + 3) / 4, 256, 0, stream>>>(hA, hB, rowPtr, csrPack,
                                              sa_w, sa_al, sa_ar, saTab, 1);
  k_gt<<<N_NODES / 4, 256, 0, stream>>>(qb, kvB, epTab, feats_sem,
                                        rowPtr, csrPack, agg);
  k_bnstats<<<256, 256, 0, stream>>>(agg, colsum, colssq);
  k_bnfinal<<<1, 256, 0, stream>>>(colsum, colssq, muArr, invArr);
  k_final<<<N_NODES / 4, 256, 0, stream>>>(agg, muArr, invArr, bn_gamma, bn_beta,
                                           Wout, bout, hB, cent, gamma, beta, out);
}

// Round 13
// 414.203 us; speedup vs baseline: 1.0309x; 1.0309x over previous
//
#include <hip/hip_runtime.h>
#include <hip/hip_bf16.h>
#include <math.h>

#define N_NODES 20000
#define N_EDGES 256000
#define LOG2E 1.4426950408889634f

typedef __attribute__((ext_vector_type(8))) __bf16 bf16x8;
typedef __attribute__((ext_vector_type(8))) unsigned short u16x8;
typedef __attribute__((ext_vector_type(4))) float f32x4;

static __device__ __forceinline__ unsigned short f2bf(float f) {
  unsigned u = __float_as_uint(f);
  unsigned r = (u + 0x7fffu + ((u >> 16) & 1u)) >> 16;
  return (unsigned short)r;
}
static __device__ __forceinline__ float b2f(unsigned short u) {
  return __uint_as_float((unsigned)u << 16);
}

// ---------------- fused setup: tables | transposes (LDS-tiled) | convX | hist ----------------
// segments: [0,1) tables, [1,449) transposes (256 Ws1 tiles + 192 QKV tiles),
//           [449,5449) convX, [5449,6449) hist
__global__ __launch_bounds__(256) void k_setup(
    const float* __restrict__ rel_emb, const float* __restrict__ sa_We,
    const float* __restrict__ We_gt, const float* __restrict__ Xs,
    const float* __restrict__ Xm, const float* __restrict__ Ws1,
    const float* __restrict__ Wq, const float* __restrict__ Wk,
    const float* __restrict__ Wv, const int* __restrict__ e_dst,
    float* __restrict__ saTab, float* __restrict__ epTab,
    ushort* __restrict__ Xsb, ushort* __restrict__ Xmb,
    ushort* __restrict__ Ws1t, ushort* __restrict__ Wt,
    int* __restrict__ deg) {
  __shared__ float tl[32][33];
  int b = blockIdx.x;
  int t = threadIdx.x;
  if (b == 0) {
    {
      int l = t >> 7, r = (t >> 3) & 15, h = t & 7;
      float acc = 0.f;
      for (int p = 0; p < 32; ++p)
        acc += rel_emb[r * 32 + p] * sa_We[l * 256 + p * 8 + h];
      saTab[t] = acc * LOG2E;
    }
    for (int r = 0; r < 16; ++r) {
      float acc = 0.f;
      for (int p = 0; p < 32; ++p)
        acc += rel_emb[r * 32 + p] * We_gt[p * 256 + t];
      epTab[r * 256 + t] = acc;
    }
  } else if (b < 449) {
    int lb = b - 1;
    int r = t >> 5, c = t & 31;
    if (lb < 256) {
      // Ws1 [8][256 d][128 k] -> Ws1t [8][128 k][256 d]
      int h = lb >> 5, idx = lb & 31;
      int k0 = (idx >> 3) * 32, d0 = (idx & 7) * 32;
      const float* src = Ws1 + (size_t)h * 32768;
      #pragma unroll
      for (int i = 0; i < 4; ++i)
        tl[r + i * 8][c] = src[(size_t)(d0 + r + i * 8) * 128 + k0 + c];
      __syncthreads();
      ushort* dst = Ws1t + (size_t)h * 32768;
      #pragma unroll
      for (int i = 0; i < 4; ++i)
        dst[(size_t)(k0 + r + i * 8) * 256 + d0 + c] = f2bf(tl[c][r + i * 8]);
    } else {
      // W[256 d][256 n] -> Wt[m][256 n][256 d]
      int qi = lb - 256;
      int m = qi >> 6, idx = qi & 63;
      int n0 = (idx >> 3) * 32, d0 = (idx & 7) * 32;
      const float* src = (m == 0) ? Wq : (m == 1) ? Wk : Wv;
      #pragma unroll
      for (int i = 0; i < 4; ++i)
        tl[r + i * 8][c] = src[(size_t)(d0 + r + i * 8) * 256 + n0 + c];
      __syncthreads();
      ushort* dst = Wt + (size_t)m * 65536;
      #pragma unroll
      for (int i = 0; i < 4; ++i)
        dst[(size_t)(n0 + r + i * 8) * 256 + d0 + c] = f2bf(tl[c][r + i * 8]);
    }
  } else if (b < 5449) {
    size_t i = ((size_t)(b - 449) * 256 + t) * 4;
    float4 a = *(const float4*)(Xs + i);
    ushort4 ua = {f2bf(a.x), f2bf(a.y), f2bf(a.z), f2bf(a.w)};
    *(ushort4*)(Xsb + i) = ua;
    float4 c4 = *(const float4*)(Xm + i);
    ushort4 uc = {f2bf(c4.x), f2bf(c4.y), f2bf(c4.z), f2bf(c4.w)};
    *(ushort4*)(Xmb + i) = uc;
  } else {
    int e = (b - 5449) * 256 + t;
    if (e < N_EDGES) atomicAdd(&deg[e_dst[e]], 1);
  }
}

__global__ __launch_bounds__(1024) void k_scan(const int* __restrict__ deg,
                                               int* __restrict__ rowPtr,
                                               int* __restrict__ cursor) {
  const int CH = (N_NODES + 1023) / 1024;  // 20
  int t = threadIdx.x;
  int b0 = t * CH, b1 = min(b0 + CH, N_NODES);
  int s = 0;
  for (int i = b0; i < b1; ++i) s += deg[i];
  __shared__ int part[1024];
  part[t] = s;
  __syncthreads();
  for (int off = 1; off < 1024; off <<= 1) {
    int add = (t >= off) ? part[t - off] : 0;
    __syncthreads();
    part[t] += add;
    __syncthreads();
  }
  int run = (t == 0) ? 0 : part[t - 1];
  for (int i = b0; i < b1; ++i) {
    rowPtr[i] = run;
    cursor[i] = run;
    run += deg[i];
  }
  if (t == 0) rowPtr[N_NODES] = part[1023];
}

__global__ void k_fill(const int* __restrict__ e_dst, const int* __restrict__ e_src,
                       const int* __restrict__ e_type, int* __restrict__ cursor,
                       int2* __restrict__ csrPack) {
  int e = blockIdx.x * 256 + threadIdx.x;
  if (e >= N_EDGES) return;
  int d = e_dst[e];
  int pos = atomicAdd(&cursor[d], 1);
  csrPack[pos] = make_int2(e_src[e], e_type[e]);
}

// ---------------- fused GEMM: full-K single-stage, one barrier, 128KiB XOR-swizzled LDS ----------------
// grid (157, 14), 512 threads (8 waves). Tile 128 nodes x 128 cols x FULL K=256.
// y<8: MLP head y (A=Xsb); y>=8: QKV slice y-8 (A=Xmb).
__global__ __launch_bounds__(512) void k_gemm(
    const ushort* __restrict__ Xsb, const ushort* __restrict__ Xmb,
    const ushort* __restrict__ Ws1t, const ushort* __restrict__ Wqkvt,
    const float* __restrict__ bs1, const float* __restrict__ Ws2,
    const float* __restrict__ bs2, const float* __restrict__ bq,
    const float* __restrict__ bk, const float* __restrict__ bv,
    float* __restrict__ h0, float* __restrict__ q, ushort* __restrict__ kvB) {
  __shared__ ushort Ab[128][256];  // full K=256 per row; elem col ^= (row&7)<<3
  __shared__ ushort Bb[128][256];  // 128 KiB total (gfx950 allows up to 160 KiB/WG)
  int tid = threadIdx.x;
  int y = blockIdx.y;
  bool isMlp = (y < 8);
  int m = 0, half = 0;
  const ushort* Bsrc;
  const ushort* Xb;
  if (isMlp) {
    Xb = Xsb;
    Bsrc = Ws1t + (size_t)y * 128 * 256;
  } else {
    int s = y - 8;
    m = s >> 1;
    half = s & 1;
    Xb = Xmb;
    Bsrc = Wqkvt + ((size_t)m * 256 + half * 128) * 256;
  }
  int base = blockIdx.x * 128;

  // ---- single full-K stage: 4 threads/row, 8 x 16B segs each for A and B ----
  {
    int r = tid >> 2, cq = (tid & 3) * 8;
    int gr = base + r;
    const ushort* asrc = Xb + (size_t)gr * 256;
    const ushort* bsrc = Bsrc + (size_t)r * 256;
    int sw = (r & 7) << 3;
    #pragma unroll
    for (int s = 0; s < 8; ++s) {
      int colc = (cq + s) * 8;        // element col in [0,256)
      int csw = colc ^ sw;
      u16x8 av = {0, 0, 0, 0, 0, 0, 0, 0};
      if (gr < N_NODES) av = *(const u16x8*)(asrc + colc);
      *(u16x8*)&Ab[r][csw] = av;
      *(u16x8*)&Bb[r][csw] = *(const u16x8*)(bsrc + colc);
    }
  }
  __syncthreads();

  int wv = tid >> 6, lane = tid & 63;
  int l15 = lane & 15, lhi = lane >> 4;
  int swzA = (l15 & 7) << 3;  // rows read are {wv,nt}*16+l15 -> row&7 == l15&7
  f32x4 acc[8];
  #pragma unroll
  for (int nt = 0; nt < 8; ++nt) acc[nt] = (f32x4){0.f, 0.f, 0.f, 0.f};

  #pragma unroll
  for (int kk = 0; kk < 8; ++kk) {
    int col = kk * 32 + lhi * 8;    // [0,256)
    bf16x8 a = *(const bf16x8*)&Ab[wv * 16 + l15][col ^ swzA];
    #pragma unroll
    for (int nt = 0; nt < 8; ++nt) {
      bf16x8 b = *(const bf16x8*)&Bb[nt * 16 + l15][col ^ swzA];
      acc[nt] = __builtin_amdgcn_mfma_f32_16x16x32_bf16(a, b, acc[nt], 0, 0, 0);
    }
  }

  if (isMlp) {
    float part[4] = {0.f, 0.f, 0.f, 0.f};
    #pragma unroll
    for (int nt = 0; nt < 8; ++nt) {
      int c = y * 128 + nt * 16 + l15;
      float b1 = bs1[c], w2 = Ws2[c];
      #pragma unroll
      for (int j = 0; j < 4; ++j)
        part[j] += fmaxf(acc[nt][j] + b1, 0.f) * w2;
    }
    #pragma unroll
    for (int j = 0; j < 4; ++j) {
      #pragma unroll
      for (int o = 1; o < 16; o <<= 1) part[j] += __shfl_xor(part[j], o);
    }
    if (l15 == 0) {
      float b2 = bs2[y];
      #pragma unroll
      for (int j = 0; j < 4; ++j) {
        int row = base + wv * 16 + lhi * 4 + j;
        if (row < N_NODES) h0[(size_t)row * 8 + y] = part[j] + b2;
      }
    }
  } else {
    const float* bias = (m == 0) ? bq : (m == 1) ? bk : bv;
    #pragma unroll
    for (int nt = 0; nt < 8; ++nt) {
      int c = half * 128 + nt * 16 + l15;
      float bc = bias[c];
      #pragma unroll
      for (int j = 0; j < 4; ++j) {
        int row = base + wv * 16 + lhi * 4 + j;
        if (row < N_NODES) {
          float val = acc[nt][j] + bc;
          if (m == 0) q[(size_t)row * 256 + c] = val;
          else if (m == 1) kvB[(size_t)row * 512 + c] = f2bf(val);
          else kvB[(size_t)row * 512 + 256 + c] = f2bf(val);
        }
      }
    }
  }
}

// ---------------- SA layers (wave per node: 8 heads x 8 edge-slots, exp2 domain) ----------------

__global__ __launch_bounds__(256) void k_sa(const float* __restrict__ h_in,
                                            float* __restrict__ h_out,
                                            const int* __restrict__ rowPtr,
                                            const int2* __restrict__ csrPack,
                                            const float* __restrict__ sa_w,
                                            const float* __restrict__ sa_al,
                                            const float* __restrict__ sa_ar,
                                            const float* __restrict__ saTab, int layer) {
  int node = blockIdx.x * 4 + (threadIdx.x >> 6);
  int lane = threadIdx.x & 63;
  int h = lane & 7, eslot = lane >> 3;
  float wgt = sa_w[layer * 8 + h];
  float al2 = sa_al[layer * 8 + h] * LOG2E;
  float ar2 = sa_ar[layer * 8 + h] * LOG2E;
  const float* tab = saTab + layer * 128;
  float zd = h_in[(size_t)node * 8 + h] * wgt;
  int s0 = rowPtr[node], s1 = rowPtr[node + 1];
  float m = -1e30f, lsum = 0.f, acc = 0.f;
  for (int i = s0 + eslot; i < s1; i += 8) {
    int2 p = csrPack[i];
    float zs = h_in[(size_t)p.x * 8 + h] * wgt;
    float e = zs * al2 + zd * ar2 + tab[p.y * 8 + h];
    e = (e >= 0.f) ? e : 0.2f * e;
    float nm = fmaxf(m, e);
    float scl = exp2f(m - nm);
    float pw = exp2f(e - nm);
    acc = acc * scl + pw * zs;
    lsum = lsum * scl + pw;
    m = nm;
  }
  #pragma unroll
  for (int off = 8; off < 64; off <<= 1) {
    float om = __shfl_xor(m, off);
    float ol = __shfl_xor(lsum, off);
    float oa = __shfl_xor(acc, off);
    float nm = fmaxf(m, om);
    float sl = exp2f(m - nm);
    float so = exp2f(om - nm);
    acc = acc * sl + oa * so;
    lsum = lsum * sl + ol * so;
    m = nm;
  }
  float o = acc / (lsum + 1e-9f);
  float r = o + zd;
  r = (r > 0.f) ? r : expm1f(r);
  if (layer == 0) {
    r += __shfl_xor(r, 1);
    r += __shfl_xor(r, 2);
    r += __shfl_xor(r, 4);
    r *= 0.125f;
  }
  if (eslot == 0) h_out[(size_t)node * 8 + h] = r;
}

// ---------------- GT edge phase (interleaved bf16 kv gather, exp2 domain) ----------------

__global__ __launch_bounds__(256) void k_gt(const float* __restrict__ q,
                                            const ushort* __restrict__ kvB,
                                            const float* __restrict__ epTab,
                                            const float* __restrict__ feats_sem,
                                            const int* __restrict__ rowPtr,
                                            const int2* __restrict__ csrPack,
                                            ushort* __restrict__ agg) {
  int node = blockIdx.x * 4 + (threadIdx.x >> 6);
  int lane = threadIdx.x & 63;
  int c0 = lane * 4;
  const float SC2 = 0.17677669529663687f * LOG2E;
  float4 qv = *(const float4*)(q + (size_t)node * 256 + c0);
  qv.x *= SC2; qv.y *= SC2; qv.z *= SC2; qv.w *= SC2;
  float4 acc = {0.f, 0.f, 0.f, 0.f};
  float m = -1e30f, lsum = 0.f;
  int s0 = rowPtr[node], s1 = rowPtr[node + 1];
  int i = s0;
  for (; i + 1 < s1; i += 2) {
    int2 eA = csrPack[i], eB = csrPack[i + 1];
    const ushort* rA = kvB + (size_t)eA.x * 512 + c0;
    const ushort* rB = kvB + (size_t)eB.x * 512 + c0;
    ushort4 kA = *(const ushort4*)rA;
    ushort4 kB4 = *(const ushort4*)rB;
    float4 epA = *(const float4*)(epTab + eA.y * 256 + c0);
    float4 epB = *(const float4*)(epTab + eB.y * 256 + c0);
    ushort4 vA = *(const ushort4*)(rA + 256);
    ushort4 vB = *(const ushort4*)(rB + 256);
    float pA = qv.x * b2f(kA.x) * epA.x + qv.y * b2f(kA.y) * epA.y +
               qv.z * b2f(kA.z) * epA.z + qv.w * b2f(kA.w) * epA.w;
    float pB = qv.x * b2f(kB4.x) * epB.x + qv.y * b2f(kB4.y) * epB.y +
               qv.z * b2f(kB4.z) * epB.z + qv.w * b2f(kB4.w) * epB.w;
    pA += __shfl_xor(pA, 1); pB += __shfl_xor(pB, 1);
    pA += __shfl_xor(pA, 2); pB += __shfl_xor(pB, 2);
    pA += __shfl_xor(pA, 4); pB += __shfl_xor(pB, 4);
    float nm = fmaxf(m, fmaxf(pA, pB));
    float scl = exp2f(m - nm);
    float wA = exp2f(pA - nm);
    float wB = exp2f(pB - nm);
    acc.x = acc.x * scl + wA * b2f(vA.x) + wB * b2f(vB.x);
    acc.y = acc.y * scl + wA * b2f(vA.y) + wB * b2f(vB.y);
    acc.z = acc.z * scl + wA * b2f(vA.z) + wB * b2f(vB.z);
    acc.w = acc.w * scl + wA * b2f(vA.w) + wB * b2f(vB.w);
    lsum = lsum * scl + wA + wB;
    m = nm;
  }
  if (i < s1) {
    int2 eA = csrPack[i];
    const ushort* rA = kvB + (size_t)eA.x * 512 + c0;
    ushort4 kv = *(const ushort4*)rA;
    float4 ep = *(const float4*)(epTab + eA.y * 256 + c0);
    ushort4 vv = *(const ushort4*)(rA + 256);
    float part = qv.x * b2f(kv.x) * ep.x + qv.y * b2f(kv.y) * ep.y +
                 qv.z * b2f(kv.z) * ep.z + qv.w * b2f(kv.w) * ep.w;
    part += __shfl_xor(part, 1);
    part += __shfl_xor(part, 2);
    part += __shfl_xor(part, 4);
    float nm = fmaxf(m, part);
    float scl = exp2f(m - nm);
    float pw = exp2f(part - nm);
    acc.x = acc.x * scl + pw * b2f(vv.x);
    acc.y = acc.y * scl + pw * b2f(vv.y);
    acc.z = acc.z * scl + pw * b2f(vv.z);
    acc.w = acc.w * scl + pw * b2f(vv.w);
    lsum = lsum * scl + pw;
    m = nm;
  }
  float inv = 1.f / (lsum + 1e-9f);
  float4 fs = *(const float4*)(feats_sem + (size_t)node * 256 + c0);
  ushort4 r;
  r.x = f2bf(acc.x * inv + fs.x);
  r.y = f2bf(acc.y * inv + fs.y);
  r.z = f2bf(acc.z * inv + fs.z);
  r.w = f2bf(acc.w * inv + fs.w);
  *(ushort4*)(agg + (size_t)node * 256 + c0) = r;
}

__global__ void k_bnstats(const ushort* __restrict__ agg, double* __restrict__ colsum,
                          double* __restrict__ colssq) {
  int t = threadIdx.x;
  int r0 = blockIdx.x * 79;
  int r1 = min(r0 + 79, N_NODES);
  double s = 0.0, qq = 0.0;
  for (int r = r0; r < r1; ++r) {
    float x = b2f(agg[(size_t)r * 256 + t]);
    s += (double)x;
    qq += (double)x * (double)x;
  }
  atomicAdd(&colsum[t], s);
  atomicAdd(&colssq[t], qq);
}

__global__ void k_bnfinal(const double* __restrict__ colsum, const double* __restrict__ colssq,
                          float* __restrict__ muArr, float* __restrict__ invArr) {
  int t = threadIdx.x;
  double mu = colsum[t] / (double)N_NODES;
  double var = colssq[t] / (double)N_NODES - mu * mu;
  muArr[t] = (float)mu;
  invArr[t] = (float)(1.0 / sqrt(var + 1e-5));
}

__global__ __launch_bounds__(256) void k_final(const ushort* __restrict__ agg,
                                               const float* __restrict__ muArr,
                                               const float* __restrict__ invArr,
                                               const float* __restrict__ bn_gamma,
                                               const float* __restrict__ bn_beta,
                                               const float* __restrict__ Wout,
                                               const float* __restrict__ bout,
                                               const float* __restrict__ hB,
                                               const float* __restrict__ cent,
                                               const float* __restrict__ gamma,
                                               const float* __restrict__ beta,
                                               float* __restrict__ out) {
  int node = blockIdx.x * 4 + (threadIdx.x >> 6);
  int lane = threadIdx.x & 63;
  int c0 = lane * 4;
  ushort4 xa = *(const ushort4*)(agg + (size_t)node * 256 + c0);
  float4 mu = *(const float4*)(muArr + c0);
  float4 iv = *(const float4*)(invArr + c0);
  float4 g = *(const float4*)(bn_gamma + c0);
  float4 b = *(const float4*)(bn_beta + c0);
  float4 w = *(const float4*)(Wout + c0);
  float p = fmaxf((b2f(xa.x) - mu.x) * iv.x * g.x + b.x, 0.f) * w.x +
            fmaxf((b2f(xa.y) - mu.y) * iv.y * g.y + b.y, 0.f) * w.y +
            fmaxf((b2f(xa.z) - mu.z) * iv.z * g.z + b.z, 0.f) * w.z +
            fmaxf((b2f(xa.w) - mu.w) * iv.w * g.w + b.w, 0.f) * w.w;
  #pragma unroll
  for (int o = 1; o < 64; o <<= 1) p += __shfl_xor(p, o);
  float ls = p + bout[0];
  int h = lane & 7;
  float logit = 0.5f * hB[(size_t)node * 8 + h] + 0.5f * ls;
  float sc = (cent[node] * gamma[h] + beta[h]) * logit;
  sc += __shfl_xor(sc, 1);
  sc += __shfl_xor(sc, 2);
  sc += __shfl_xor(sc, 4);
  float mn = sc * 0.125f;
  mn = (mn >= 0.f) ? mn : 0.01f * mn;
  if (lane == 0) out[node] = mn;
}

// ---------------- launch ----------------

extern "C" void kernel_launch(void* const* d_in, const int* in_sizes, int n_in,
                              void* d_out, int out_size, void* d_ws, size_t ws_size,
                              hipStream_t stream) {
  (void)in_sizes; (void)n_in; (void)out_size; (void)ws_size;
  const float* feats_struct = (const float*)d_in[0];
  const float* feats_sem    = (const float*)d_in[1];
  const float* cent         = (const float*)d_in[2];
  const float* Ws1          = (const float*)d_in[3];
  const float* bs1          = (const float*)d_in[4];
  const float* Ws2          = (const float*)d_in[5];
  const float* bs2          = (const float*)d_in[6];
  const float* rel_emb      = (const float*)d_in[7];
  const float* sa_w         = (const float*)d_in[8];
  const float* sa_al        = (const float*)d_in[9];
  const float* sa_ar        = (const float*)d_in[10];
  const float* sa_We        = (const float*)d_in[11];
  const float* Wq           = (const float*)d_in[12];
  const float* bq           = (const float*)d_in[13];
  const float* Wk           = (const float*)d_in[14];
  const float* bk           = (const float*)d_in[15];
  const float* Wv           = (const float*)d_in[16];
  const float* bv           = (const float*)d_in[17];
  const float* We_gt        = (const float*)d_in[18];
  const float* bn_gamma     = (const float*)d_in[19];
  const float* bn_beta      = (const float*)d_in[20];
  const float* Wout         = (const float*)d_in[21];
  const float* bout         = (const float*)d_in[22];
  const float* gamma        = (const float*)d_in[23];
  const float* beta         = (const float*)d_in[24];
  const int* e_type         = (const int*)d_in[25];
  const int* e_src          = (const int*)d_in[26];
  const int* e_dst          = (const int*)d_in[27];
  float* out = (float*)d_out;

  char* wsb = (char*)d_ws;
  size_t off = 0;
  auto alloc = [&](size_t bytes) -> char* {
    char* p = wsb + off;
    off = (off + bytes + 255) & ~(size_t)255;
    return p;
  };
  float* saTab   = (float*)alloc(2 * 16 * 8 * 4);
  float* epTab   = (float*)alloc(16 * 256 * 4);
  int* deg       = (int*)alloc((size_t)N_NODES * 4);
  int* rowPtr    = (int*)alloc((size_t)(N_NODES + 1) * 4);
  int* cursor    = (int*)alloc((size_t)N_NODES * 4);
  int2* csrPack  = (int2*)alloc((size_t)N_EDGES * 8);
  float* h0      = (float*)alloc((size_t)N_NODES * 8 * 4);
  float* hA      = (float*)alloc((size_t)N_NODES * 8 * 4);
  float* hB      = (float*)alloc((size_t)N_NODES * 8 * 4);
  float* qb      = (float*)alloc((size_t)N_NODES * 256 * 4);
  ushort* kvB    = (ushort*)alloc((size_t)N_NODES * 512 * 2);
  ushort* agg    = (ushort*)alloc((size_t)N_NODES * 256 * 2);
  double* colsum = (double*)alloc(256 * 8);
  double* colssq = (double*)alloc(256 * 8);
  float* muArr   = (float*)alloc(256 * 4);
  float* invArr  = (float*)alloc(256 * 4);
  ushort* Xsb    = (ushort*)alloc((size_t)N_NODES * 256 * 2);
  ushort* Xmb    = (ushort*)alloc((size_t)N_NODES * 256 * 2);
  ushort* Ws1t   = (ushort*)alloc((size_t)8 * 128 * 256 * 2);
  ushort* Wqkvt  = (ushort*)alloc((size_t)3 * 256 * 256 * 2);

  hipMemsetAsync(deg, 0, (size_t)N_NODES * 4, stream);
  hipMemsetAsync(colsum, 0, 256 * 8, stream);
  hipMemsetAsync(colssq, 0, 256 * 8, stream);

  k_setup<<<6449, 256, 0, stream>>>(rel_emb, sa_We, We_gt, feats_struct, feats_sem,
                                    Ws1, Wq, Wk, Wv, e_dst,
                                    saTab, epTab, Xsb, Xmb, Ws1t, Wqkvt, deg);
  k_scan<<<1, 1024, 0, stream>>>(deg, rowPtr, cursor);
  k_fill<<<(N_EDGES + 255) / 256, 256, 0, stream>>>(e_dst, e_src, e_type, cursor, csrPack);

  const int MT = (N_NODES + 127) / 128;  // 157
  dim3 gGemm(MT, 14);
  k_gemm<<<gGemm, 512, 0, stream>>>(Xsb, Xmb, Ws1t, Wqkvt, bs1, Ws2, bs2,
                                    bq, bk, bv, h0, qb, kvB);
  k_sa<<<(N_NODES + 3) / 4, 256, 0, stream>>>(h0, hA, rowPtr, csrPack,
                                              sa_w, sa_al, sa_ar, saTab, 0);
  k_sa<<<(N_NODES + 3) / 4, 256, 0, stream>>>(hA, hB, rowPtr, csrPack,
                                              sa_w, sa_al, sa_ar, saTab, 1);
  k_gt<<<N_NODES / 4, 256, 0, stream>>>(qb, kvB, epTab, feats_sem,
                                        rowPtr, csrPack, agg);
  k_bnstats<<<256, 256, 0, stream>>>(agg, colsum, colssq);
  k_bnfinal<<<1, 256, 0, stream>>>(colsum, colssq, muArr, invArr);
  k_final<<<N_NODES / 4, 256, 0, stream>>>(agg, muArr, invArr, bn_gamma, bn_beta,
                                           Wout, bout, hB, cent, gamma, beta, out);
}

// Round 14
// 364.954 us; speedup vs baseline: 1.1700x; 1.1349x over previous
//
#include <hip/hip_runtime.h>
#include <hip/hip_bf16.h>
#include <math.h>

#define N_NODES 20000
#define N_EDGES 256000
#define LOG2E 1.4426950408889634f

typedef __attribute__((ext_vector_type(8))) __bf16 bf16x8;
typedef __attribute__((ext_vector_type(8))) unsigned short u16x8;
typedef __attribute__((ext_vector_type(4))) float f32x4;

static __device__ __forceinline__ unsigned short f2bf(float f) {
  unsigned u = __float_as_uint(f);
  unsigned r = (u + 0x7fffu + ((u >> 16) & 1u)) >> 16;
  return (unsigned short)r;
}
static __device__ __forceinline__ float b2f(unsigned short u) {
  return __uint_as_float((unsigned)u << 16);
}

// ---------------- fused setup: tables | transposes (LDS-tiled) | convX | hist ----------------
// segments: [0,1) tables, [1,449) transposes, [449,5449) convX, [5449,6449) hist
__global__ __launch_bounds__(256) void k_setup(
    const float* __restrict__ rel_emb, const float* __restrict__ sa_We,
    const float* __restrict__ We_gt, const float* __restrict__ Xs,
    const float* __restrict__ Xm, const float* __restrict__ Ws1,
    const float* __restrict__ Wq, const float* __restrict__ Wk,
    const float* __restrict__ Wv, const int* __restrict__ e_dst,
    float* __restrict__ saTab, float* __restrict__ epTab,
    ushort* __restrict__ Xsb, ushort* __restrict__ Xmb,
    ushort* __restrict__ Ws1t, ushort* __restrict__ Wt,
    int* __restrict__ deg) {
  __shared__ float tl[32][33];
  int b = blockIdx.x;
  int t = threadIdx.x;
  if (b == 0) {
    {
      int l = t >> 7, r = (t >> 3) & 15, h = t & 7;
      float acc = 0.f;
      for (int p = 0; p < 32; ++p)
        acc += rel_emb[r * 32 + p] * sa_We[l * 256 + p * 8 + h];
      saTab[t] = acc * LOG2E;
    }
    for (int r = 0; r < 16; ++r) {
      float acc = 0.f;
      for (int p = 0; p < 32; ++p)
        acc += rel_emb[r * 32 + p] * We_gt[p * 256 + t];
      epTab[r * 256 + t] = acc;
    }
  } else if (b < 449) {
    int lb = b - 1;
    int r = t >> 5, c = t & 31;
    if (lb < 256) {
      int h = lb >> 5, idx = lb & 31;
      int k0 = (idx >> 3) * 32, d0 = (idx & 7) * 32;
      const float* src = Ws1 + (size_t)h * 32768;
      #pragma unroll
      for (int i = 0; i < 4; ++i)
        tl[r + i * 8][c] = src[(size_t)(d0 + r + i * 8) * 128 + k0 + c];
      __syncthreads();
      ushort* dst = Ws1t + (size_t)h * 32768;
      #pragma unroll
      for (int i = 0; i < 4; ++i)
        dst[(size_t)(k0 + r + i * 8) * 256 + d0 + c] = f2bf(tl[c][r + i * 8]);
    } else {
      int qi = lb - 256;
      int m = qi >> 6, idx = qi & 63;
      int n0 = (idx >> 3) * 32, d0 = (idx & 7) * 32;
      const float* src = (m == 0) ? Wq : (m == 1) ? Wk : Wv;
      #pragma unroll
      for (int i = 0; i < 4; ++i)
        tl[r + i * 8][c] = src[(size_t)(d0 + r + i * 8) * 256 + n0 + c];
      __syncthreads();
      ushort* dst = Wt + (size_t)m * 65536;
      #pragma unroll
      for (int i = 0; i < 4; ++i)
        dst[(size_t)(n0 + r + i * 8) * 256 + d0 + c] = f2bf(tl[c][r + i * 8]);
    }
  } else if (b < 5449) {
    size_t i = ((size_t)(b - 449) * 256 + t) * 4;
    float4 a = *(const float4*)(Xs + i);
    ushort4 ua = {f2bf(a.x), f2bf(a.y), f2bf(a.z), f2bf(a.w)};
    *(ushort4*)(Xsb + i) = ua;
    float4 c4 = *(const float4*)(Xm + i);
    ushort4 uc = {f2bf(c4.x), f2bf(c4.y), f2bf(c4.z), f2bf(c4.w)};
    *(ushort4*)(Xmb + i) = uc;
  } else {
    int e = (b - 5449) * 256 + t;
    if (e < N_EDGES) atomicAdd(&deg[e_dst[e]], 1);
  }
}

__global__ __launch_bounds__(1024) void k_scan(const int* __restrict__ deg,
                                               int* __restrict__ rowPtr,
                                               int* __restrict__ cursor) {
  const int CH = (N_NODES + 1023) / 1024;  // 20
  int t = threadIdx.x;
  int b0 = t * CH, b1 = min(b0 + CH, N_NODES);
  int s = 0;
  for (int i = b0; i < b1; ++i) s += deg[i];
  __shared__ int part[1024];
  part[t] = s;
  __syncthreads();
  for (int off = 1; off < 1024; off <<= 1) {
    int add = (t >= off) ? part[t - off] : 0;
    __syncthreads();
    part[t] += add;
    __syncthreads();
  }
  int run = (t == 0) ? 0 : part[t - 1];
  for (int i = b0; i < b1; ++i) {
    rowPtr[i] = run;
    cursor[i] = run;
    run += deg[i];
  }
  if (t == 0) rowPtr[N_NODES] = part[1023];
}

__global__ void k_fill(const int* __restrict__ e_dst, const int* __restrict__ e_src,
                       const int* __restrict__ e_type, int* __restrict__ cursor,
                       int2* __restrict__ csrPack) {
  int e = blockIdx.x * 256 + threadIdx.x;
  if (e >= N_EDGES) return;
  int d = e_dst[e];
  int pos = atomicAdd(&cursor[d], 1);
  csrPack[pos] = make_int2(e_src[e], e_type[e]);
}

// ---------------- fused GEMM: register-resident A, LDS B per output slice ----------------
// grid (313, 2), 256 threads (4 waves), 64 rows/block; wave holds 16 rows x K=256 of A in regs.
// y=0: loop 8 MLP head-slices (A=Xsb); y=1: loop 6 QKV slices (A=Xmb).
__global__ __launch_bounds__(256) void k_gemm(
    const ushort* __restrict__ Xsb, const ushort* __restrict__ Xmb,
    const ushort* __restrict__ Ws1t, const ushort* __restrict__ Wqkvt,
    const float* __restrict__ bs1, const float* __restrict__ Ws2,
    const float* __restrict__ bs2, const float* __restrict__ bq,
    const float* __restrict__ bk, const float* __restrict__ bv,
    float* __restrict__ h0, float* __restrict__ q, ushort* __restrict__ kvB) {
  __shared__ ushort Bb[128][256];  // 64KB; elem col ^= (row&7)<<3
  int tid = threadIdx.x;
  int y = blockIdx.y;
  int base = blockIdx.x * 64;
  int wv = tid >> 6, lane = tid & 63;
  int l15 = lane & 15, lhi = lane >> 4;
  int rowbase = base + wv * 16;

  // ---- load A once: 16 rows x 256 K per wave, directly from bf16 X ----
  const ushort* Xb = (y == 0) ? Xsb : Xmb;
  bf16x8 A[8];
  {
    int row = rowbase + l15;
    bool ok = row < N_NODES;
    const ushort* rp = Xb + (size_t)row * 256;
    #pragma unroll
    for (int kk = 0; kk < 8; ++kk) {
      u16x8 v = {0, 0, 0, 0, 0, 0, 0, 0};
      if (ok) v = *(const u16x8*)(rp + kk * 32 + lhi * 8);
      A[kk] = *(bf16x8*)&v;
    }
  }

  int nSlices = (y == 0) ? 8 : 6;
  int swz = (l15 & 7) << 3;
  for (int sl = 0; sl < nSlices; ++sl) {
    const ushort* Bsrc;
    if (y == 0) {
      Bsrc = Ws1t + (size_t)sl * 128 * 256;
    } else {
      int m = sl >> 1, half = sl & 1;
      Bsrc = Wqkvt + ((size_t)m * 256 + half * 128) * 256;
    }
    __syncthreads();  // all waves done reading Bb from previous slice
    // stage B: 128 rows x 256 elems; 32 threads/row (contiguous 512B), 16 passes
    #pragma unroll
    for (int ps = 0; ps < 16; ++ps) {
      int r = ps * 8 + (tid >> 5);
      int ce = (tid & 31) * 8;
      int csw = ce ^ ((r & 7) << 3);
      *(u16x8*)&Bb[r][csw] = *(const u16x8*)(Bsrc + (size_t)r * 256 + ce);
    }
    __syncthreads();

    f32x4 acc[8];
    #pragma unroll
    for (int nt = 0; nt < 8; ++nt) acc[nt] = (f32x4){0.f, 0.f, 0.f, 0.f};
    #pragma unroll
    for (int kk = 0; kk < 8; ++kk) {
      int col = kk * 32 + lhi * 8;
      #pragma unroll
      for (int nt = 0; nt < 8; ++nt) {
        bf16x8 b = *(const bf16x8*)&Bb[nt * 16 + l15][col ^ swz];
        acc[nt] = __builtin_amdgcn_mfma_f32_16x16x32_bf16(A[kk], b, acc[nt], 0, 0, 0);
      }
    }

    if (y == 0) {
      int h = sl;
      float part[4] = {0.f, 0.f, 0.f, 0.f};
      #pragma unroll
      for (int nt = 0; nt < 8; ++nt) {
        int c = h * 128 + nt * 16 + l15;
        float b1 = bs1[c], w2 = Ws2[c];
        #pragma unroll
        for (int j = 0; j < 4; ++j)
          part[j] += fmaxf(acc[nt][j] + b1, 0.f) * w2;
      }
      #pragma unroll
      for (int j = 0; j < 4; ++j) {
        #pragma unroll
        for (int o = 1; o < 16; o <<= 1) part[j] += __shfl_xor(part[j], o);
      }
      if (l15 == 0) {
        float b2 = bs2[h];
        #pragma unroll
        for (int j = 0; j < 4; ++j) {
          int row = rowbase + lhi * 4 + j;
          if (row < N_NODES) h0[(size_t)row * 8 + h] = part[j] + b2;
        }
      }
    } else {
      int m = sl >> 1, half = sl & 1;
      const float* bias = (m == 0) ? bq : (m == 1) ? bk : bv;
      #pragma unroll
      for (int nt = 0; nt < 8; ++nt) {
        int c = half * 128 + nt * 16 + l15;
        float bc = bias[c];
        #pragma unroll
        for (int j = 0; j < 4; ++j) {
          int row = rowbase + lhi * 4 + j;
          if (row < N_NODES) {
            float val = acc[nt][j] + bc;
            if (m == 0) q[(size_t)row * 256 + c] = val;
            else if (m == 1) kvB[(size_t)row * 512 + c] = f2bf(val);
            else kvB[(size_t)row * 512 + 256 + c] = f2bf(val);
          }
        }
      }
    }
  }
}

// ---------------- SA layers (wave per node: 8 heads x 8 edge-slots, exp2 domain) ----------------

__global__ __launch_bounds__(256) void k_sa(const float* __restrict__ h_in,
                                            float* __restrict__ h_out,
                                            const int* __restrict__ rowPtr,
                                            const int2* __restrict__ csrPack,
                                            const float* __restrict__ sa_w,
                                            const float* __restrict__ sa_al,
                                            const float* __restrict__ sa_ar,
                                            const float* __restrict__ saTab, int layer) {
  int node = blockIdx.x * 4 + (threadIdx.x >> 6);
  int lane = threadIdx.x & 63;
  int h = lane & 7, eslot = lane >> 3;
  float wgt = sa_w[layer * 8 + h];
  float al2 = sa_al[layer * 8 + h] * LOG2E;
  float ar2 = sa_ar[layer * 8 + h] * LOG2E;
  const float* tab = saTab + layer * 128;
  float zd = h_in[(size_t)node * 8 + h] * wgt;
  int s0 = rowPtr[node], s1 = rowPtr[node + 1];
  float m = -1e30f, lsum = 0.f, acc = 0.f;
  for (int i = s0 + eslot; i < s1; i += 8) {
    int2 p = csrPack[i];
    float zs = h_in[(size_t)p.x * 8 + h] * wgt;
    float e = zs * al2 + zd * ar2 + tab[p.y * 8 + h];
    e = (e >= 0.f) ? e : 0.2f * e;
    float nm = fmaxf(m, e);
    float scl = exp2f(m - nm);
    float pw = exp2f(e - nm);
    acc = acc * scl + pw * zs;
    lsum = lsum * scl + pw;
    m = nm;
  }
  #pragma unroll
  for (int off = 8; off < 64; off <<= 1) {
    float om = __shfl_xor(m, off);
    float ol = __shfl_xor(lsum, off);
    float oa = __shfl_xor(acc, off);
    float nm = fmaxf(m, om);
    float sl = exp2f(m - nm);
    float so = exp2f(om - nm);
    acc = acc * sl + oa * so;
    lsum = lsum * sl + ol * so;
    m = nm;
  }
  float o = acc / (lsum + 1e-9f);
  float r = o + zd;
  r = (r > 0.f) ? r : expm1f(r);
  if (layer == 0) {
    r += __shfl_xor(r, 1);
    r += __shfl_xor(r, 2);
    r += __shfl_xor(r, 4);
    r *= 0.125f;
  }
  if (eslot == 0) h_out[(size_t)node * 8 + h] = r;
}

// ---------------- GT edge phase (interleaved bf16 kv gather, exp2 domain) ----------------

__global__ __launch_bounds__(256) void k_gt(const float* __restrict__ q,
                                            const ushort* __restrict__ kvB,
                                            const float* __restrict__ epTab,
                                            const float* __restrict__ feats_sem,
                                            const int* __restrict__ rowPtr,
                                            const int2* __restrict__ csrPack,
                                            ushort* __restrict__ agg) {
  int node = blockIdx.x * 4 + (threadIdx.x >> 6);
  int lane = threadIdx.x & 63;
  int c0 = lane * 4;
  const float SC2 = 0.17677669529663687f * LOG2E;
  float4 qv = *(const float4*)(q + (size_t)node * 256 + c0);
  qv.x *= SC2; qv.y *= SC2; qv.z *= SC2; qv.w *= SC2;
  float4 acc = {0.f, 0.f, 0.f, 0.f};
  float m = -1e30f, lsum = 0.f;
  int s0 = rowPtr[node], s1 = rowPtr[node + 1];
  int i = s0;
  for (; i + 1 < s1; i += 2) {
    int2 eA = csrPack[i], eB = csrPack[i + 1];
    const ushort* rA = kvB + (size_t)eA.x * 512 + c0;
    const ushort* rB = kvB + (size_t)eB.x * 512 + c0;
    ushort4 kA = *(const ushort4*)rA;
    ushort4 kB4 = *(const ushort4*)rB;
    float4 epA = *(const float4*)(epTab + eA.y * 256 + c0);
    float4 epB = *(const float4*)(epTab + eB.y * 256 + c0);
    ushort4 vA = *(const ushort4*)(rA + 256);
    ushort4 vB = *(const ushort4*)(rB + 256);
    float pA = qv.x * b2f(kA.x) * epA.x + qv.y * b2f(kA.y) * epA.y +
               qv.z * b2f(kA.z) * epA.z + qv.w * b2f(kA.w) * epA.w;
    float pB = qv.x * b2f(kB4.x) * epB.x + qv.y * b2f(kB4.y) * epB.y +
               qv.z * b2f(kB4.z) * epB.z + qv.w * b2f(kB4.w) * epB.w;
    pA += __shfl_xor(pA, 1); pB += __shfl_xor(pB, 1);
    pA += __shfl_xor(pA, 2); pB += __shfl_xor(pB, 2);
    pA += __shfl_xor(pA, 4); pB += __shfl_xor(pB, 4);
    float nm = fmaxf(m, fmaxf(pA, pB));
    float scl = exp2f(m - nm);
    float wA = exp2f(pA - nm);
    float wB = exp2f(pB - nm);
    acc.x = acc.x * scl + wA * b2f(vA.x) + wB * b2f(vB.x);
    acc.y = acc.y * scl + wA * b2f(vA.y) + wB * b2f(vB.y);
    acc.z = acc.z * scl + wA * b2f(vA.z) + wB * b2f(vB.z);
    acc.w = acc.w * scl + wA * b2f(vA.w) + wB * b2f(vB.w);
    lsum = lsum * scl + wA + wB;
    m = nm;
  }
  if (i < s1) {
    int2 eA = csrPack[i];
    const ushort* rA = kvB + (size_t)eA.x * 512 + c0;
    ushort4 kv = *(const ushort4*)rA;
    float4 ep = *(const float4*)(epTab + eA.y * 256 + c0);
    ushort4 vv = *(const ushort4*)(rA + 256);
    float part = qv.x * b2f(kv.x) * ep.x + qv.y * b2f(kv.y) * ep.y +
                 qv.z * b2f(kv.z) * ep.z + qv.w * b2f(kv.w) * ep.w;
    part += __shfl_xor(part, 1);
    part += __shfl_xor(part, 2);
    part += __shfl_xor(part, 4);
    float nm = fmaxf(m, part);
    float scl = exp2f(m - nm);
    float pw = exp2f(part - nm);
    acc.x = acc.x * scl + pw * b2f(vv.x);
    acc.y = acc.y * scl + pw * b2f(vv.y);
    acc.z = acc.z * scl + pw * b2f(vv.z);
    acc.w = acc.w * scl + pw * b2f(vv.w);
    lsum = lsum * scl + pw;
    m = nm;
  }
  float inv = 1.f / (lsum + 1e-9f);
  float4 fs = *(const float4*)(feats_sem + (size_t)node * 256 + c0);
  ushort4 r;
  r.x = f2bf(acc.x * inv + fs.x);
  r.y = f2bf(acc.y * inv + fs.y);
  r.z = f2bf(acc.z * inv + fs.z);
  r.w = f2bf(acc.w * inv + fs.w);
  *(ushort4*)(agg + (size_t)node * 256 + c0) = r;
}

__global__ void k_bnstats(const ushort* __restrict__ agg, double* __restrict__ colsum,
                          double* __restrict__ colssq) {
  int t = threadIdx.x;
  int r0 = blockIdx.x * 79;
  int r1 = min(r0 + 79, N_NODES);
  double s = 0.0, qq = 0.0;
  for (int r = r0; r < r1; ++r) {
    float x = b2f(agg[(size_t)r * 256 + t]);
    s += (double)x;
    qq += (double)x * (double)x;
  }
  atomicAdd(&colsum[t], s);
  atomicAdd(&colssq[t], qq);
}

__global__ void k_bnfinal(const double* __restrict__ colsum, const double* __restrict__ colssq,
                          float* __restrict__ muArr, float* __restrict__ invArr) {
  int t = threadIdx.x;
  double mu = colsum[t] / (double)N_NODES;
  double var = colssq[t] / (double)N_NODES - mu * mu;
  muArr[t] = (float)mu;
  invArr[t] = (float)(1.0 / sqrt(var + 1e-5));
}

__global__ __launch_bounds__(256) void k_final(const ushort* __restrict__ agg,
                                               const float* __restrict__ muArr,
                                               const float* __restrict__ invArr,
                                               const float* __restrict__ bn_gamma,
                                               const float* __restrict__ bn_beta,
                                               const float* __restrict__ Wout,
                                               const float* __restrict__ bout,
                                               const float* __restrict__ hB,
                                               const float* __restrict__ cent,
                                               const float* __restrict__ gamma,
                                               const float* __restrict__ beta,
                                               float* __restrict__ out) {
  int node = blockIdx.x * 4 + (threadIdx.x >> 6);
  int lane = threadIdx.x & 63;
  int c0 = lane * 4;
  ushort4 xa = *(const ushort4*)(agg + (size_t)node * 256 + c0);
  float4 mu = *(const float4*)(muArr + c0);
  float4 iv = *(const float4*)(invArr + c0);
  float4 g = *(const float4*)(bn_gamma + c0);
  float4 b = *(const float4*)(bn_beta + c0);
  float4 w = *(const float4*)(Wout + c0);
  float p = fmaxf((b2f(xa.x) - mu.x) * iv.x * g.x + b.x, 0.f) * w.x +
            fmaxf((b2f(xa.y) - mu.y) * iv.y * g.y + b.y, 0.f) * w.y +
            fmaxf((b2f(xa.z) - mu.z) * iv.z * g.z + b.z, 0.f) * w.z +
            fmaxf((b2f(xa.w) - mu.w) * iv.w * g.w + b.w, 0.f) * w.w;
  #pragma unroll
  for (int o = 1; o < 64; o <<= 1) p += __shfl_xor(p, o);
  float ls = p + bout[0];
  int h = lane & 7;
  float logit = 0.5f * hB[(size_t)node * 8 + h] + 0.5f * ls;
  float sc = (cent[node] * gamma[h] + beta[h]) * logit;
  sc += __shfl_xor(sc, 1);
  sc += __shfl_xor(sc, 2);
  sc += __shfl_xor(sc, 4);
  float mn = sc * 0.125f;
  mn = (mn >= 0.f) ? mn : 0.01f * mn;
  if (lane == 0) out[node] = mn;
}

// ---------------- launch ----------------

extern "C" void kernel_launch(void* const* d_in, const int* in_sizes, int n_in,
                              void* d_out, int out_size, void* d_ws, size_t ws_size,
                              hipStream_t stream) {
  (void)in_sizes; (void)n_in; (void)out_size; (void)ws_size;
  const float* feats_struct = (const float*)d_in[0];
  const float* feats_sem    = (const float*)d_in[1];
  const float* cent         = (const float*)d_in[2];
  const float* Ws1          = (const float*)d_in[3];
  const float* bs1          = (const float*)d_in[4];
  const float* Ws2          = (const float*)d_in[5];
  const float* bs2          = (const float*)d_in[6];
  const float* rel_emb      = (const float*)d_in[7];
  const float* sa_w         = (const float*)d_in[8];
  const float* sa_al        = (const float*)d_in[9];
  const float* sa_ar        = (const float*)d_in[10];
  const float* sa_We        = (const float*)d_in[11];
  const float* Wq           = (const float*)d_in[12];
  const float* bq           = (const float*)d_in[13];
  const float* Wk           = (const float*)d_in[14];
  const float* bk           = (const float*)d_in[15];
  const float* Wv           = (const float*)d_in[16];
  const float* bv           = (const float*)d_in[17];
  const float* We_gt        = (const float*)d_in[18];
  const float* bn_gamma     = (const float*)d_in[19];
  const float* bn_beta      = (const float*)d_in[20];
  const float* Wout         = (const float*)d_in[21];
  const float* bout         = (const float*)d_in[22];
  const float* gamma        = (const float*)d_in[23];
  const float* beta         = (const float*)d_in[24];
  const int* e_type         = (const int*)d_in[25];
  const int* e_src          = (const int*)d_in[26];
  const int* e_dst          = (const int*)d_in[27];
  float* out = (float*)d_out;

  char* wsb = (char*)d_ws;
  size_t off = 0;
  auto alloc = [&](size_t bytes) -> char* {
    char* p = wsb + off;
    off = (off + bytes + 255) & ~(size_t)255;
    return p;
  };
  float* saTab   = (float*)alloc(2 * 16 * 8 * 4);
  float* epTab   = (float*)alloc(16 * 256 * 4);
  int* deg       = (int*)alloc((size_t)N_NODES * 4);
  int* rowPtr    = (int*)alloc((size_t)(N_NODES + 1) * 4);
  int* cursor    = (int*)alloc((size_t)N_NODES * 4);
  int2* csrPack  = (int2*)alloc((size_t)N_EDGES * 8);
  float* h0      = (float*)alloc((size_t)N_NODES * 8 * 4);
  float* hA      = (float*)alloc((size_t)N_NODES * 8 * 4);
  float* hB      = (float*)alloc((size_t)N_NODES * 8 * 4);
  float* qb      = (float*)alloc((size_t)N_NODES * 256 * 4);
  ushort* kvB    = (ushort*)alloc((size_t)N_NODES * 512 * 2);
  ushort* agg    = (ushort*)alloc((size_t)N_NODES * 256 * 2);
  double* colsum = (double*)alloc(256 * 8);
  double* colssq = (double*)alloc(256 * 8);
  float* muArr   = (float*)alloc(256 * 4);
  float* invArr  = (float*)alloc(256 * 4);
  ushort* Xsb    = (ushort*)alloc((size_t)N_NODES * 256 * 2);
  ushort* Xmb    = (ushort*)alloc((size_t)N_NODES * 256 * 2);
  ushort* Ws1t   = (ushort*)alloc((size_t)8 * 128 * 256 * 2);
  ushort* Wqkvt  = (ushort*)alloc((size_t)3 * 256 * 256 * 2);

  hipMemsetAsync(deg, 0, (size_t)N_NODES * 4, stream);
  hipMemsetAsync(colsum, 0, 256 * 8, stream);
  hipMemsetAsync(colssq, 0, 256 * 8, stream);

  k_setup<<<6449, 256, 0, stream>>>(rel_emb, sa_We, We_gt, feats_struct, feats_sem,
                                    Ws1, Wq, Wk, Wv, e_dst,
                                    saTab, epTab, Xsb, Xmb, Ws1t, Wqkvt, deg);
  k_scan<<<1, 1024, 0, stream>>>(deg, rowPtr, cursor);
  k_fill<<<(N_EDGES + 255) / 256, 256, 0, stream>>>(e_dst, e_src, e_type, cursor, csrPack);

  const int MT = (N_NODES + 63) / 64;  // 313
  dim3 gGemm(MT, 2);
  k_gemm<<<gGemm, 256, 0, stream>>>(Xsb, Xmb, Ws1t, Wqkvt, bs1, Ws2, bs2,
                                    bq, bk, bv, h0, qb, kvB);
  k_sa<<<(N_NODES + 3) / 4, 256, 0, stream>>>(h0, hA, rowPtr, csrPack,
                                              sa_w, sa_al, sa_ar, saTab, 0);
  k_sa<<<(N_NODES + 3) / 4, 256, 0, stream>>>(hA, hB, rowPtr, csrPack,
                                              sa_w, sa_al, sa_ar, saTab, 1);
  k_gt<<<N_NODES / 4, 256, 0, stream>>>(qb, kvB, epTab, feats_sem,
                                        rowPtr, csrPack, agg);
  k_bnstats<<<256, 256, 0, stream>>>(agg, colsum, colssq);
  k_bnfinal<<<1, 256, 0, stream>>>(colsum, colssq, muArr, invArr);
  k_final<<<N_NODES / 4, 256, 0, stream>>>(agg, muArr, invArr, bn_gamma, bn_beta,
                                           Wout, bout, hB, cent, gamma, beta, out);
}